// Round 7
// baseline (446.229 us; speedup 1.0000x reference)
//
#include <hip/hip_runtime.h>
#include <hip/hip_bf16.h>
#include <math.h>

#define NN 100000
#define NE 3200000
#define NPAD 100096
#define NB 391        // buckets: dst>>8, 256 nodes each (ceil(100000/256))
#define BN 256        // nodes per bucket
#define EPB 8192      // edges per block in hist/scatter passes
#define NBLK 391      // ceil(NE/EPB)
#define SBUF 9728     // LDS staging capacity in fine (bucket mean 8192, +17 sigma)

typedef __attribute__((ext_vector_type(8))) short short8;
typedef __attribute__((ext_vector_type(4))) float floatx4;

// ---------------- bf16 helpers (storage bf16, math fp32) ----------------
__device__ __forceinline__ unsigned short bf16_of(float x) {
    __hip_bfloat16 h = __float2bfloat16(x);  // RNE
    return *(unsigned short*)&h;
}
__device__ __forceinline__ unsigned pack2(float a, float b) {
    return (unsigned)bf16_of(a) | ((unsigned)bf16_of(b) << 16);
}
__device__ __forceinline__ float lo_f(unsigned u) { return __uint_as_float(u << 16); }
__device__ __forceinline__ float hi_f(unsigned u) { return __uint_as_float(u & 0xffff0000u); }

// ---------------- pass A: per-block bucket histogram (bucket-major out) ----------------
__global__ __launch_bounds__(256) void hist_kernel(const int* __restrict__ dst,
                                                   int* __restrict__ blkhist) {
    __shared__ int cnt[NB];
    int t = threadIdx.x;
    for (int i = t; i < NB; i += 256) cnt[i] = 0;
    __syncthreads();
    int e0 = blockIdx.x * EPB;
    int e1 = min(e0 + EPB, NE);
    for (int e = e0 + t; e < e1; e += 256) atomicAdd(&cnt[dst[e] >> 8], 1);
    __syncthreads();
    for (int i = t; i < NB; i += 256) blkhist[i * NBLK + blockIdx.x] = cnt[i];
}

// ---------------- pass B1: per-bucket exclusive scan along blocks ----------------
__global__ __launch_bounds__(64) void scanA_kernel(int* __restrict__ blkhist,
                                                   int* __restrict__ totals) {
    int j = blockIdx.x, lane = threadIdx.x;
    int base = j * NBLK;
    int carry = 0;
    for (int c = 0; c < NBLK; c += 64) {
        int b = c + lane;
        int v = (b < NBLK) ? blkhist[base + b] : 0;
        int inc = v;
#pragma unroll
        for (int m = 1; m < 64; m <<= 1) {
            int u = __shfl_up(inc, m, 64);
            if (lane >= m) inc += u;
        }
        if (b < NBLK) blkhist[base + b] = carry + inc - v;
        carry += __shfl(inc, 63, 64);
    }
    if (lane == 0) totals[j] = carry;
}

// ---------------- pass B2: bucket bases ----------------
__global__ __launch_bounds__(256) void scanB_kernel(const int* __restrict__ totals,
                                                    int* __restrict__ bucket_base) {
    __shared__ int sm[NB];
    int t = threadIdx.x;
    for (int i = t; i < NB; i += 256) sm[i] = totals[i];
    __syncthreads();
    if (t == 0) {
        int r = 0;
        for (int i = 0; i < NB; ++i) { bucket_base[i] = r; r += sm[i]; }
        bucket_base[NB] = r;
    }
}

// ---------------- pass C: LDS-staged scatter -> contiguous run writes ----------------
__global__ __launch_bounds__(256) void scatter_kernel(const int* __restrict__ src,
                                                      const int* __restrict__ dst,
                                                      const int* __restrict__ blkhist,
                                                      const int* __restrict__ bucket_base,
                                                      int* __restrict__ staged) {
    __shared__ int cnt[NB];
    __shared__ int lbase[NB + 1];
    __shared__ int gbase[NB];
    __shared__ int sbuf[EPB];             // 32KB
    __shared__ unsigned short sbkt[EPB];  // 16KB: bucket id per slot
    int t = threadIdx.x;
    for (int i = t; i < NB; i += 256) cnt[i] = 0;
    __syncthreads();
    int e0 = blockIdx.x * EPB;
    int e1 = min(e0 + EPB, NE);
    int cn = e1 - e0;
    for (int e = e0 + t; e < e1; e += 256) atomicAdd(&cnt[dst[e] >> 8], 1);
    __syncthreads();
    if (t < 64) {  // exclusive scan of 391 counts, 7 per lane
        int v[7]; int s = 0;
#pragma unroll
        for (int k = 0; k < 7; ++k) { int idx = t * 7 + k; v[k] = (idx < NB) ? cnt[idx] : 0; s += v[k]; }
        int inc = s;
#pragma unroll
        for (int m = 1; m < 64; m <<= 1) {
            int u = __shfl_up(inc, m, 64);
            if (t >= m) inc += u;
        }
        int run = inc - s;
#pragma unroll
        for (int k = 0; k < 7; ++k) { int idx = t * 7 + k; if (idx < NB) lbase[idx] = run; run += v[k]; }
        if (t == 63) lbase[NB] = inc;  // == cn
    }
    __syncthreads();
    for (int i = t; i < NB; i += 256) {
        gbase[i] = bucket_base[i] + blkhist[i * NBLK + blockIdx.x];
        cnt[i] = lbase[i];            // rank cursors
    }
    __syncthreads();
    for (int e = e0 + t; e < e1; e += 256) {
        int s = src[e], d = dst[e];
        int bk = d >> 8;
        int r = atomicAdd(&cnt[bk], 1);     // LDS atomic
        sbuf[r] = (s << 8) | (d & (BN - 1));
        sbkt[r] = (unsigned short)bk;
    }
    __syncthreads();
    for (int i = t; i < cn; i += 256) {     // contiguous run write-out
        int bk = sbkt[i];
        staged[gbase[bk] + i - lbase[bk]] = sbuf[i];
    }
}

// ---------------- pass D: per-bucket fine counting sort + offsets + dis ----------------
// Bucket segment buffered in LDS (single global read); fallback to global reads
// if a bucket improbably exceeds SBUF.
__global__ __launch_bounds__(256) void fine_kernel(const int* __restrict__ staged,
                                                   const int* __restrict__ bucket_base,
                                                   int* __restrict__ offset,
                                                   float* __restrict__ dis,
                                                   int* __restrict__ csr_src) {
    __shared__ int hist[BN];
    __shared__ int offs[BN];
    __shared__ int cur[BN];
    __shared__ int sb[SBUF];   // 38.9KB
    int t = threadIdx.x, j = blockIdx.x;
    int bb = bucket_base[j], be = bucket_base[j + 1];
    int cn = be - bb;
    bool lds_ok = (cn <= SBUF);
    for (int i = t; i < BN; i += 256) hist[i] = 0;
    __syncthreads();
    if (lds_ok) {
        for (int e = t; e < cn; e += 256) {
            int p = staged[bb + e];
            sb[e] = p;
            atomicAdd(&hist[p & (BN - 1)], 1);
        }
    } else {
        for (int e = t; e < cn; e += 256) atomicAdd(&hist[staged[bb + e] & (BN - 1)], 1);
    }
    __syncthreads();
    if (t < 64) {  // wave0: exclusive scan of 256 counts
        int v[4]; int s = 0;
#pragma unroll
        for (int k = 0; k < 4; ++k) { v[k] = hist[t * 4 + k]; s += v[k]; }
        int inc = s;
#pragma unroll
        for (int m = 1; m < 64; m <<= 1) {
            int u = __shfl_up(inc, m, 64);
            if (t >= m) inc += u;
        }
        int run = inc - s;
#pragma unroll
        for (int k = 0; k < 4; ++k) { offs[t * 4 + k] = run; run += v[k]; }
    }
    __syncthreads();
    if (t < BN) {
        cur[t] = offs[t];
        int n = j * BN + t;
        if (n < NN) {
            offset[n] = bb + offs[t];
            dis[n] = rsqrtf((float)hist[t] + 1.0f);
        }
    }
    if (j == NB - 1 && t == 0) offset[NN] = NE;
    __syncthreads();
    for (int e = t; e < cn; e += 256) {
        int p = lds_ok ? sb[e] : staged[bb + e];
        int r = atomicAdd(&cur[p & (BN - 1)], 1);  // LDS atomic
        csr_src[bb + r] = p >> 8;
    }
}

// ---------------- matmul 1 (MFMA): ys1 = bf16(dis * (x @ W1)), plane-major out -------
// Planes: ys1[ch][node][16], ch = col tile tt.
__global__ __launch_bounds__(256) void mm1_kernel(const float* __restrict__ x,
                                                  const float* __restrict__ W,
                                                  const float* __restrict__ dis,
                                                  unsigned short* __restrict__ y) {
    __shared__ unsigned short Wt[64][136];  // W^T bf16: [n][k], pad 8 shorts
    int t = threadIdx.x;
    for (int i = t; i < 128 * 64; i += 256) {
        int k = i >> 6, n = i & 63;
        Wt[n][k] = bf16_of(W[i]);
    }
    __syncthreads();
    int wave = t >> 6, lane = t & 63;
    int quad = lane >> 4, n16 = lane & 15;
    short8 bfr[4][4];  // [kstep][coltile]
#pragma unroll
    for (int s = 0; s < 4; ++s)
#pragma unroll
        for (int tt = 0; tt < 4; ++tt)
            bfr[s][tt] = *(const short8*)&Wt[tt * 16 + n16][s * 32 + quad * 8];
    int tile0 = (blockIdx.x * 4 + wave) * 4;   // 391 blocks x 4 waves x 4 tiles >= 6250
#pragma unroll 1
    for (int it = 0; it < 4; ++it) {
        int tile = tile0 + it;
        if (tile >= 6250) break;
        int m0 = tile * 16;
        const float* xp = x + (size_t)(m0 + n16) * 128 + quad * 8;
        floatx4 acc0 = {0,0,0,0}, acc1 = {0,0,0,0}, acc2 = {0,0,0,0}, acc3 = {0,0,0,0};
#pragma unroll
        for (int s = 0; s < 4; ++s) {
            float4 lo = *(const float4*)(xp + s * 32);
            float4 hi = *(const float4*)(xp + s * 32 + 4);
            short8 a;
            a[0] = (short)bf16_of(lo.x); a[1] = (short)bf16_of(lo.y);
            a[2] = (short)bf16_of(lo.z); a[3] = (short)bf16_of(lo.w);
            a[4] = (short)bf16_of(hi.x); a[5] = (short)bf16_of(hi.y);
            a[6] = (short)bf16_of(hi.z); a[7] = (short)bf16_of(hi.w);
            acc0 = __builtin_amdgcn_mfma_f32_16x16x32_bf16(a, bfr[s][0], acc0, 0, 0, 0);
            acc1 = __builtin_amdgcn_mfma_f32_16x16x32_bf16(a, bfr[s][1], acc1, 0, 0, 0);
            acc2 = __builtin_amdgcn_mfma_f32_16x16x32_bf16(a, bfr[s][2], acc2, 0, 0, 0);
            acc3 = __builtin_amdgcn_mfma_f32_16x16x32_bf16(a, bfr[s][3], acc3, 0, 0, 0);
        }
#pragma unroll
        for (int r = 0; r < 4; ++r) {
            int ro = m0 + quad * 4 + r;
            float sc = dis[ro];
            y[((size_t)0 * NN + ro) * 16 + n16] = bf16_of(acc0[r] * sc);
            y[((size_t)1 * NN + ro) * 16 + n16] = bf16_of(acc1[r] * sc);
            y[((size_t)2 * NN + ro) * 16 + n16] = bf16_of(acc2[r] * sc);
            y[((size_t)3 * NN + ro) * 16 + n16] = bf16_of(acc3[r] * sc);
        }
    }
}

// ---------------- matmul 2 (MFMA): ys2 = bf16(dis * (h @ W2)); h & ys2 plane-major ---
__global__ __launch_bounds__(256) void mm2_kernel(const unsigned short* __restrict__ h,
                                                  const float* __restrict__ W,
                                                  const float* __restrict__ dis,
                                                  unsigned short* __restrict__ y) {
    __shared__ unsigned short Wt[32][72];  // W^T bf16: [n][k], pad 8
    int t = threadIdx.x;
    for (int i = t; i < 64 * 32; i += 256) {
        int k = i >> 5, n = i & 31;
        Wt[n][k] = bf16_of(W[i]);
    }
    __syncthreads();
    int wave = t >> 6, lane = t & 63;
    int quad = lane >> 4, n16 = lane & 15;
    short8 bfr[2][2];
#pragma unroll
    for (int s = 0; s < 2; ++s)
#pragma unroll
        for (int tt = 0; tt < 2; ++tt)
            bfr[s][tt] = *(const short8*)&Wt[tt * 16 + n16][s * 32 + quad * 8];
    int tile0 = (blockIdx.x * 4 + wave) * 4;
#pragma unroll 1
    for (int it = 0; it < 4; ++it) {
        int tile = tile0 + it;
        if (tile >= 6250) break;
        int m0 = tile * 16;
        floatx4 acc0 = {0,0,0,0}, acc1 = {0,0,0,0};
#pragma unroll
        for (int s = 0; s < 2; ++s) {
            // feats f = s*32 + quad*8 -> plane p = s*2 + (quad>>1), off = (quad&1)*8
            const unsigned short* hp =
                h + ((size_t)(s * 2 + (quad >> 1)) * NN + (m0 + n16)) * 16 + (quad & 1) * 8;
            short8 a = *(const short8*)hp;
            acc0 = __builtin_amdgcn_mfma_f32_16x16x32_bf16(a, bfr[s][0], acc0, 0, 0, 0);
            acc1 = __builtin_amdgcn_mfma_f32_16x16x32_bf16(a, bfr[s][1], acc1, 0, 0, 0);
        }
#pragma unroll
        for (int r = 0; r < 4; ++r) {
            int ro = m0 + quad * 4 + r;
            float sc = dis[ro];
            y[((size_t)0 * NN + ro) * 16 + n16] = bf16_of(acc0[r] * sc);
            y[((size_t)1 * NN + ro) * 16 + n16] = bf16_of(acc1[r] * sc);
        }
    }
}

// ---------------- chunked gather-aggregate over one 16-feat plane ----------------
// 8 lanes/node, 4B (2 feats) per lane. ysp/outp are unsigned (2x bf16) planes.
__global__ __launch_bounds__(256) void aggc_kernel(const unsigned* __restrict__ ysp,
                                                   const float* __restrict__ dis,
                                                   const int* __restrict__ offset,
                                                   const int* __restrict__ csr_src,
                                                   const float* __restrict__ b,
                                                   unsigned* __restrict__ outp,
                                                   int do_relu) {
    int tid = blockIdx.x * 256 + threadIdx.x;
    int nd = tid >> 3, c8 = tid & 7;
    if (nd >= NN) return;
    int start = offset[nd], end = offset[nd + 1];
    float a0, a1;
    { unsigned u = ysp[nd * 8 + c8]; a0 = lo_f(u); a1 = hi_f(u); }  // self-loop
    int i = start;
    int n8 = start + ((end - start) & ~7);
    for (; i < n8; i += 8) {
        int s0 = csr_src[i],     s1 = csr_src[i + 1], s2 = csr_src[i + 2], s3 = csr_src[i + 3];
        int s4 = csr_src[i + 4], s5 = csr_src[i + 5], s6 = csr_src[i + 6], s7 = csr_src[i + 7];
        unsigned u0 = ysp[s0 * 8 + c8], u1 = ysp[s1 * 8 + c8];
        unsigned u2 = ysp[s2 * 8 + c8], u3 = ysp[s3 * 8 + c8];
        unsigned u4 = ysp[s4 * 8 + c8], u5 = ysp[s5 * 8 + c8];
        unsigned u6 = ysp[s6 * 8 + c8], u7 = ysp[s7 * 8 + c8];
        a0 += lo_f(u0); a1 += hi_f(u0); a0 += lo_f(u1); a1 += hi_f(u1);
        a0 += lo_f(u2); a1 += hi_f(u2); a0 += lo_f(u3); a1 += hi_f(u3);
        a0 += lo_f(u4); a1 += hi_f(u4); a0 += lo_f(u5); a1 += hi_f(u5);
        a0 += lo_f(u6); a1 += hi_f(u6); a0 += lo_f(u7); a1 += hi_f(u7);
    }
    for (; i < end; ++i) {
        unsigned u = ysp[csr_src[i] * 8 + c8];
        a0 += lo_f(u); a1 += hi_f(u);
    }
    float ds = dis[nd];
    float r0 = fmaf(ds, a0, b[c8 * 2]);
    float r1 = fmaf(ds, a1, b[c8 * 2 + 1]);
    if (do_relu) { r0 = fmaxf(r0, 0.f); r1 = fmaxf(r1, 0.f); }
    outp[nd * 8 + c8] = pack2(r0, r1);
}

// ---------------- chunked decode: partial dot over one 16-feat plane ----------------
// 4 lanes/edge, 8B per lane from each of z[src], z[dst].
__global__ __launch_bounds__(256) void decodec_kernel(const uint2* __restrict__ zp,
                                                      const int* __restrict__ src,
                                                      const int* __restrict__ dst,
                                                      float* __restrict__ partial,
                                                      float* __restrict__ out,
                                                      int final_) {
    int tid = blockIdx.x * 256 + threadIdx.x;
    int e = tid >> 2, k = tid & 3;
    if (e >= NE) return;
    int s = src[e], d = dst[e];
    uint2 za = zp[s * 4 + k];
    uint2 zb = zp[d * 4 + k];
    float acc = lo_f(za.x) * lo_f(zb.x) + hi_f(za.x) * hi_f(zb.x)
              + lo_f(za.y) * lo_f(zb.y) + hi_f(za.y) * hi_f(zb.y);
    acc += __shfl_xor(acc, 1, 4);
    acc += __shfl_xor(acc, 2, 4);
    if (k == 0) {
        if (!final_) partial[e] = acc;
        else out[e] = 1.0f / (1.0f + expf(-(partial[e] + acc)));
    }
}

// ---------------- launcher ----------------
extern "C" void kernel_launch(void* const* d_in, const int* in_sizes, int n_in,
                              void* d_out, int out_size, void* d_ws, size_t ws_size,
                              hipStream_t stream) {
    const float* emb = (const float*)d_in[0];
    const float* W1  = (const float*)d_in[1];
    const float* b1  = (const float*)d_in[2];
    const float* W2  = (const float*)d_in[3];
    const float* b2  = (const float*)d_in[4];
    const int*   ei  = (const int*)d_in[5];
    const int* src = ei;
    const int* dst = ei + NE;
    float* out = (float*)d_out;

    // workspace layout
    char* w = (char*)d_ws;
    int*   offset      = (int*)w;           w += (size_t)NPAD * 4;
    float* dis         = (float*)w;         w += (size_t)NPAD * 4;
    int*   bucket_base = (int*)w;           w += 2048;
    int*   totals      = (int*)w;           w += 2048;
    int*   blkhist     = (int*)w;           w += (size_t)NB * NBLK * 4 + 1024;  // ~612KB
    int*   csr_src     = (int*)w;           w += (size_t)NE * 4;                // 12.8MB
    int*   staged      = (int*)w;           w += (size_t)NE * 4;                // 12.8MB
    unsigned short* ysbuf = (unsigned short*)w; w += (size_t)NN * 64 * 2;       // 12.8MB
    unsigned short* h  = (unsigned short*)w;                                    // 12.8MB
    // plane-major regions
    unsigned short* ys1 = ysbuf;                     // [4][NN][16]
    unsigned short* ys2 = ysbuf;                     // [2][NN][16] overlays dead ys1
    unsigned short* z   = ysbuf + (size_t)NN * 32;   // [2][NN][16] second half
    float* partial = (float*)staged;                 // dead after fine_kernel

    // CSR build — LDS atomics only, contiguous staged writes
    hist_kernel<<<NBLK, 256, 0, stream>>>(dst, blkhist);
    scanA_kernel<<<NB, 64, 0, stream>>>(blkhist, totals);
    scanB_kernel<<<1, 256, 0, stream>>>(totals, bucket_base);
    scatter_kernel<<<NBLK, 256, 0, stream>>>(src, dst, blkhist, bucket_base, staged);
    fine_kernel<<<NB, 256, 0, stream>>>(staged, bucket_base, offset, dis, csr_src);

    // layer 1: mm1 -> 4 plane passes of aggregation (relu)
    mm1_kernel<<<391, 256, 0, stream>>>(emb, W1, dis, ys1);
    for (int c = 0; c < 4; ++c)
        aggc_kernel<<<(NN * 8 + 255) / 256, 256, 0, stream>>>(
            (const unsigned*)(ys1 + (size_t)c * NN * 16), dis, offset, csr_src,
            b1 + c * 16, (unsigned*)(h + (size_t)c * NN * 16), 1);

    // layer 2: mm2 -> 2 plane passes (no relu)
    mm2_kernel<<<391, 256, 0, stream>>>(h, W2, dis, ys2);
    for (int c = 0; c < 2; ++c)
        aggc_kernel<<<(NN * 8 + 255) / 256, 256, 0, stream>>>(
            (const unsigned*)(ys2 + (size_t)c * NN * 16), dis, offset, csr_src,
            b2 + c * 16, (unsigned*)(z + (size_t)c * NN * 16), 0);

    // decode: 2 plane passes (partial dot, then finalize + sigmoid)
    for (int p = 0; p < 2; ++p)
        decodec_kernel<<<(NE * 4) / 256, 256, 0, stream>>>(
            (const uint2*)(z + (size_t)p * NN * 16), src, dst, partial, out, p);
}